// Round 1
// baseline (225.457 us; speedup 1.0000x reference)
//
#include <hip/hip_runtime.h>
#include <stdint.h>

// GCN: out = relu(adj @ (x @ W) + b)
// x:[32,1024,128] f32, adj:[32,1024,1024] f32, W:[128,128] f32, b:[128] f32
// Strategy: bf16 MFMA (16x16x32). k0: W^T -> bf16. k1: ST[b][h][m] = (x@W)^T
// as bf16 (transposed so k2's B-fragment is contiguous). k2: adj@S + bias, relu.

typedef short bf16x8 __attribute__((ext_vector_type(8)));       // 8 bf16 (4 VGPRs)
typedef float f32x4 __attribute__((ext_vector_type(4)));
typedef int i32x4 __attribute__((ext_vector_type(4)));
typedef unsigned short u16x4 __attribute__((ext_vector_type(4)));

__device__ __forceinline__ unsigned short f2bf(float f) {
    uint32_t u = __builtin_bit_cast(uint32_t, f);
    u += 0x7FFFu + ((u >> 16) & 1u);   // RTNE
    return (unsigned short)(u >> 16);
}

// ---------------- k0: WT[h][f] = bf16(W[f][h]) ----------------
__global__ __launch_bounds__(256) void k0_wt(const float* __restrict__ W,
                                             unsigned short* __restrict__ WT) {
    int o = blockIdx.x * 256 + threadIdx.x;  // flat over [h][f]
    int h = o >> 7, f = o & 127;
    WT[o] = f2bf(W[f * 128 + h]);
}

// ---------------- k1: ST[b][h][m] = sum_f WT[h][f] * x[b][m][f] ----------------
// D'[h][m] per block: 128 h  x 64 m, K=128. A = WT frag, B = x^T frag (rows of x).
#define K1S 136  // LDS row stride (bf16): 272B = odd multiple of 16B -> uniform b128 banks
__global__ __launch_bounds__(256) void k1_support(const float* __restrict__ x,
                                                  const unsigned short* __restrict__ WT,
                                                  unsigned short* __restrict__ ST) {
    __shared__ __align__(16) unsigned short xt[64 * K1S];   // [m][f] bf16
    __shared__ __align__(16) unsigned short wt[128 * K1S];  // [h][f] bf16
    int t = threadIdx.x;
    int node_base = blockIdx.x * 64;

    // stage x tile: 64 rows x 128 f (fp32 -> bf16)
    const f32x4* xg = (const f32x4*)(x + (size_t)node_base * 128);
#pragma unroll
    for (int i = 0; i < 8; ++i) {
        int f4 = i * 256 + t;
        int row = f4 >> 5, c4 = f4 & 31;
        f32x4 v = xg[f4];
        u16x4 p;
        p.x = f2bf(v.x); p.y = f2bf(v.y); p.z = f2bf(v.z); p.w = f2bf(v.w);
        *(u16x4*)&xt[row * K1S + c4 * 4] = p;
    }
    // stage full WT (128x128 bf16), 16B chunks
    const i32x4* wg = (const i32x4*)WT;
#pragma unroll
    for (int i = 0; i < 8; ++i) {
        int c = i * 256 + t;
        int row = c >> 4, ch = c & 15;
        *(i32x4*)&wt[row * K1S + ch * 8] = wg[c];
    }
    __syncthreads();

    int wv = t >> 6, lane = t & 63, l16 = lane & 15, quad = lane >> 4;
    int wave_h = (wv & 1) * 64, wave_m = (wv >> 1) * 32;

    f32x4 acc[4][2];
#pragma unroll
    for (int ht = 0; ht < 4; ++ht)
#pragma unroll
        for (int mt = 0; mt < 2; ++mt) acc[ht][mt] = 0.f;

#pragma unroll
    for (int s = 0; s < 4; ++s) {
        int ko = s * 32 + quad * 8;
        bf16x8 a[4], bb[2];
#pragma unroll
        for (int ht = 0; ht < 4; ++ht)
            a[ht] = *(const bf16x8*)&wt[(wave_h + ht * 16 + l16) * K1S + ko];
#pragma unroll
        for (int mt = 0; mt < 2; ++mt)
            bb[mt] = *(const bf16x8*)&xt[(wave_m + mt * 16 + l16) * K1S + ko];
#pragma unroll
        for (int ht = 0; ht < 4; ++ht)
#pragma unroll
            for (int mt = 0; mt < 2; ++mt)
                acc[ht][mt] = __builtin_amdgcn_mfma_f32_16x16x32_bf16(
                    a[ht], bb[mt], acc[ht][mt], 0, 0, 0);
    }

    int batch = blockIdx.x >> 4;
    int m_in_b = (blockIdx.x & 15) * 64;
#pragma unroll
    for (int ht = 0; ht < 4; ++ht)
#pragma unroll
        for (int mt = 0; mt < 2; ++mt) {
            int mcol = wave_m + mt * 16 + l16;
#pragma unroll
            for (int r = 0; r < 4; ++r) {
                int h = wave_h + ht * 16 + quad * 4 + r;
                ST[(((size_t)batch * 128 + h) << 10) + m_in_b + mcol] =
                    f2bf(acc[ht][mt][r]);
            }
        }
}

// ---------------- k2: out[b][m][n] = relu(sum_k adj[b][m][k]*S[b][k][n] + bias[n]) ----
// Per block: 64 m-rows x 128 n (full), K=1024 in BK=64 chunks. 4 waves -> 32x64 each.
#define K2S 72  // LDS row stride (bf16): 144B = 9*16B -> uniform b128 bank slots
__global__ __launch_bounds__(256) void k2_gcn(const float* __restrict__ adj,
                                              const unsigned short* __restrict__ ST,
                                              const float* __restrict__ bias,
                                              float* __restrict__ out) {
    __shared__ __align__(16) unsigned short As[64 * K2S];   // adj tile [m][k] bf16
    __shared__ __align__(16) unsigned short Bs[128 * K2S];  // ST tile [n][k] bf16
    int t = threadIdx.x;
    int batch = blockIdx.x >> 4;
    int mbase = (blockIdx.x & 15) * 64;
    int wv = t >> 6, lane = t & 63, l16 = lane & 15, quad = lane >> 4;
    int wave_m = (wv & 1) * 32, wave_n = (wv >> 1) * 64;

    float bv[4];
#pragma unroll
    for (int j = 0; j < 4; ++j) bv[j] = bias[wave_n + j * 16 + l16];

    f32x4 acc[2][4];
#pragma unroll
    for (int i = 0; i < 2; ++i)
#pragma unroll
        for (int j = 0; j < 4; ++j) acc[i][j] = 0.f;

    const float* adjb = adj + ((size_t)batch * 1024 + mbase) * 1024;
    const unsigned short* stb = ST + ((size_t)batch * 128) * 1024;

    for (int kb = 0; kb < 16; ++kb) {
        // stage adj 64x64 fp32 -> bf16 LDS
#pragma unroll
        for (int i = 0; i < 4; ++i) {
            int f4 = i * 256 + t;
            int row = f4 >> 4, c4 = f4 & 15;
            f32x4 v = *(const f32x4*)(adjb + (size_t)row * 1024 + kb * 64 + c4 * 4);
            u16x4 p;
            p.x = f2bf(v.x); p.y = f2bf(v.y); p.z = f2bf(v.z); p.w = f2bf(v.w);
            *(u16x4*)&As[row * K2S + c4 * 4] = p;
        }
        // stage ST 128(n) x 64(k) bf16, 16B chunks
#pragma unroll
        for (int i = 0; i < 4; ++i) {
            int c = i * 256 + t;
            int row = c >> 3, ch = c & 7;
            *(i32x4*)&Bs[row * K2S + ch * 8] =
                *(const i32x4*)(stb + (size_t)row * 1024 + kb * 64 + ch * 8);
        }
        __syncthreads();
#pragma unroll
        for (int s = 0; s < 2; ++s) {
            int ko = s * 32 + quad * 8;
            bf16x8 a[2], bb[4];
#pragma unroll
            for (int i = 0; i < 2; ++i)
                a[i] = *(const bf16x8*)&As[(wave_m + i * 16 + l16) * K2S + ko];
#pragma unroll
            for (int j = 0; j < 4; ++j)
                bb[j] = *(const bf16x8*)&Bs[(wave_n + j * 16 + l16) * K2S + ko];
#pragma unroll
            for (int i = 0; i < 2; ++i)
#pragma unroll
                for (int j = 0; j < 4; ++j)
                    acc[i][j] = __builtin_amdgcn_mfma_f32_16x16x32_bf16(
                        a[i], bb[j], acc[i][j], 0, 0, 0);
        }
        __syncthreads();
    }

    float* outb = out + ((size_t)batch * 1024 + mbase) * 128;
#pragma unroll
    for (int i = 0; i < 2; ++i)
#pragma unroll
        for (int j = 0; j < 4; ++j) {
            int n = wave_n + j * 16 + l16;
#pragma unroll
            for (int r = 0; r < 4; ++r) {
                int m = wave_m + i * 16 + quad * 4 + r;
                float v = acc[i][j][r] + bv[j];
                outb[(size_t)m * 128 + n] = fmaxf(v, 0.f);
            }
        }
}

extern "C" void kernel_launch(void* const* d_in, const int* in_sizes, int n_in,
                              void* d_out, int out_size, void* d_ws, size_t ws_size,
                              hipStream_t stream) {
    const float* x = (const float*)d_in[0];
    const float* adj = (const float*)d_in[1];
    const float* W = (const float*)d_in[2];
    const float* b = (const float*)d_in[3];
    float* out = (float*)d_out;

    // ws layout: ST bf16 [32][128][1024] = 8 MiB, then WT bf16 [128][128] = 32 KiB
    unsigned short* ST = (unsigned short*)d_ws;
    unsigned short* WT = (unsigned short*)d_ws + (size_t)32 * 128 * 1024;

    k0_wt<<<64, 256, 0, stream>>>(W, WT);
    k1_support<<<512, 256, 0, stream>>>(x, WT, ST);
    k2_gcn<<<512, 256, 0, stream>>>(adj, ST, b, out);
}